// Round 3
// baseline (257.555 us; speedup 1.0000x reference)
//
#include <hip/hip_runtime.h>
#include <math.h>

// EuclideanCodebook: N=131072 rows x d=128 fp32, K=1024 codes.
// bf16x3 split-precision MFMA (xh*eh + xl*eh + xh*el), per-row top-2 gap
// tracking, exact fp32 recheck of rows with gap < TAU.
// R5: 32 rows/wave, LDS dbuf staging, 2 chains. 141 us, MfmaUtil 31%.
// R6: global->VGPR B loads (no LDS). REGRESSED 174 us: no prefetch distance.
// R7: counted vmcnt(4) + raw barriers + setprio. 156 us, MfmaUtil 29%.
//     Pipe arithmetic (corrected): MFMA 41 us, LDS-read 41 us, VALU 15 us
//     per CU. MFMA+VALU+LDS busy ~90% DISJOINT -> pipes serialize per wave;
//     LDS pipe carries 41 us because all 4 waves re-read the full B tile.
// R8 (this round): 64 rows/wave (2 row-groups per wave, 256 rows/block,
//     grid=512 = exactly 2 blocks/CU, no tail):
//     (a) LDS-read pipe halves (16 ds_read_b128 feed 48 MFMA, was 24);
//     (b) 2 interleaved acc chains give 2x per-wave MFMA ILP;
//     (c) merged chains: acc init = -||e||^2, all 3 bf16x3 products
//         accumulate in-MFMA -> epilogue is 4 VALU/score (tag,min,max,max);
//     (d) barrier count per unit work halves.
//     Register budget ~250: launch_bounds(256,2).

typedef __attribute__((ext_vector_type(8)))  short short8_t;   // 8 bf16
typedef __attribute__((ext_vector_type(16))) float floatx16;   // 32x32 C frag

constexpr int D        = 128;
constexpr int KCODES   = 1024;
constexpr int NTILES   = 32;      // 1024 / 32 codes-per-tile
constexpr int ROWS_BLK = 256;     // 4 waves x 64 rows
constexpr float TAU    = 0.015f;  // recheck margin >> 5-sigma score error (~2e-3)

// ws layout (bytes); total ~1.03 MB
constexpr size_t WS_NCSQ = 0;                      // 1024 f32, NEGATED ||e||^2
constexpr size_t WS_EHI  = 4096;                   // 1024*128 ushort, frag-ordered
constexpr size_t WS_ELO  = WS_EHI + 262144;
constexpr size_t WS_EMBT = WS_ELO + 262144;        // 128*1024 f32 transposed

#define GLOBAL_AS __attribute__((address_space(1)))
#define LDS_AS    __attribute__((address_space(3)))

__device__ inline unsigned short bf16_rne(float v, float* back) {
    unsigned u = __float_as_uint(v);
    unsigned r = (u + 0x7FFFu + ((u >> 16) & 1u)) >> 16;
    *back = __uint_as_float(r << 16);
    return (unsigned short)r;
}

// hi/lo bf16 split of 2*v for 8 elements
__device__ inline void cvt8x2(const float4 a, const float4 b,
                              short8_t* fh, short8_t* fl) {
    float vv[8] = {a.x, a.y, a.z, a.w, b.x, b.y, b.z, b.w};
    short8_t h, l;
#pragma unroll
    for (int j = 0; j < 8; ++j) {
        float v2x = vv[j] + vv[j];    // fold the score's factor-2 into A
        float hb, db;
        h[j] = (short)bf16_rne(v2x, &hb);
        l[j] = (short)bf16_rne(v2x - hb, &db);
    }
    *fh = h; *fl = l;
}

// ------- prep: ncsq + frag-ordered bf16 hi/lo codebook + transposed codebook ----
// 64 blocks x 256 threads; thread = (code n, dim-chunk cc of 8 elements).
// Frag order: short8 chunk index = (t*8 + (cc>>1))*64 + (cc&1)*32 + (n&31),
// so main's lane l reads tile t, MFMA-step s at short8 index (t*8+s)*64 + l.
__global__ __launch_bounds__(256)
void ecb_prep(const float* __restrict__ embed, float* __restrict__ ncsq,
              unsigned short* __restrict__ ehi, unsigned short* __restrict__ elo,
              float* __restrict__ embT) {
    const int tid = threadIdx.x;
    const int cc = tid & 15;            // dim chunk 0..15
    const int nl = tid >> 4;            // 0..15
    const int n  = blockIdx.x * 16 + nl;
    const int t = n >> 5, nn = n & 31;
    const float* src = embed + (size_t)n * D + cc * 8;
    float4 a = *(const float4*)src;
    float4 b = *(const float4*)(src + 4);
    float vv[8] = {a.x, a.y, a.z, a.w, b.x, b.y, b.z, b.w};
    float ss = 0.f;
    unsigned short hq[8], lq[8];
#pragma unroll
    for (int j = 0; j < 8; ++j) {
        ss = fmaf(vv[j], vv[j], ss);
        float hb, db;
        hq[j] = bf16_rne(vv[j], &hb);
        lq[j] = bf16_rne(vv[j] - hb, &db);
    }
    uint4 ph, pl;
    ph.x = (unsigned)hq[0] | ((unsigned)hq[1] << 16);
    ph.y = (unsigned)hq[2] | ((unsigned)hq[3] << 16);
    ph.z = (unsigned)hq[4] | ((unsigned)hq[5] << 16);
    ph.w = (unsigned)hq[6] | ((unsigned)hq[7] << 16);
    pl.x = (unsigned)lq[0] | ((unsigned)lq[1] << 16);
    pl.y = (unsigned)lq[2] | ((unsigned)lq[3] << 16);
    pl.z = (unsigned)lq[4] | ((unsigned)lq[5] << 16);
    pl.w = (unsigned)lq[6] | ((unsigned)lq[7] << 16);
    size_t dst = ((size_t)(t * 8 + (cc >> 1)) * 64 + (size_t)((cc & 1) * 32 + nn)) * 8;
    *(uint4*)(ehi + dst) = ph;
    *(uint4*)(elo + dst) = pl;
#pragma unroll
    for (int j = 0; j < 8; ++j) embT[(size_t)(cc * 8 + j) * KCODES + n] = vv[j];
    // csq reduce over the 16 cc-lanes (contiguous within the wave)
#pragma unroll
    for (int m = 1; m < 16; m <<= 1) ss += __shfl_xor(ss, m, 64);
    if (cc == 0) ncsq[n] = -ss;
}

// ---------------- main: MFMA scores + argmax + fused exact recheck ----------------
__global__ __launch_bounds__(256, 2)
void ecb_main(const float* __restrict__ x,
              const unsigned short* __restrict__ ehi, const unsigned short* __restrict__ elo,
              const float* __restrict__ ncsq, const float* __restrict__ embed,
              const float* __restrict__ embT,
              float* __restrict__ out_idx, float* __restrict__ out_q) {
    __shared__ short8_t ebuf[2][2][512];   // [dbuf][hi/lo][s*64+lane], 32 KB
    __shared__ float ncsq_s[KCODES];       // 4 KB
    __shared__ int   sidx[ROWS_BLK];
    __shared__ unsigned char llist[ROWS_BLK];
    __shared__ unsigned lcount;

    const int tid  = threadIdx.x;
    const int lane = tid & 63, wave = tid >> 6;
    const int col  = lane & 31, h = lane >> 5;
    const long rowblk = (long)blockIdx.x * ROWS_BLK;
    const int  roww   = wave * 64;         // 64 rows per wave (2 groups of 32)

    if (tid == 0) lcount = 0u;

    auto stage = [&](int t, int bb) {
        const char* gh = (const char*)ehi + (size_t)t * 8192;
        const char* gl = (const char*)elo + (size_t)t * 8192;
        char* lh = (char*)&ebuf[bb][0][0];
        char* ll = (char*)&ebuf[bb][1][0];
        const int off = wave * 2048;
        // 4 x global_load_lds_dwordx4 per wave = the exact vmcnt(4) quantum
        __builtin_amdgcn_global_load_lds((const GLOBAL_AS unsigned int*)(gh + off + lane * 16),
                                         (LDS_AS unsigned int*)(lh + off), 16, 0, 0);
        __builtin_amdgcn_global_load_lds((const GLOBAL_AS unsigned int*)(gh + off + 1024 + lane * 16),
                                         (LDS_AS unsigned int*)(lh + off + 1024), 16, 0, 0);
        __builtin_amdgcn_global_load_lds((const GLOBAL_AS unsigned int*)(gl + off + lane * 16),
                                         (LDS_AS unsigned int*)(ll + off), 16, 0, 0);
        __builtin_amdgcn_global_load_lds((const GLOBAL_AS unsigned int*)(gl + off + 1024 + lane * 16),
                                         (LDS_AS unsigned int*)(ll + off + 1024), 16, 0, 0);
    };

    stage(0, 0);                           // issue tile 0 ASAP; NOT drained here
    ((float4*)ncsq_s)[tid] = ((const float4*)ncsq)[tid];   // 1024 f32 -> LDS

    // A prologue: 64 rows/wave of x -> bf16 hi/lo split of (2*x) in registers.
    short8_t ah0[8], al0[8], ah1[8], al1[8];
    {
        const float* xr0 = x + (rowblk + roww + col) * (long)D + h * 8;
        const float* xr1 = xr0 + 32 * (long)D;
#pragma unroll
        for (int c = 0; c < 8; ++c) {
            cvt8x2(*(const float4*)(xr0 + c * 16), *(const float4*)(xr0 + c * 16 + 4),
                   &ah0[c], &al0[c]);
            cvt8x2(*(const float4*)(xr1 + c * 16), *(const float4*)(xr1 + c * 16 + 4),
                   &ah1[c], &al1[c]);
        }
    }

    float v1a[16], v2a[16], v1b[16], v2b[16];
#pragma unroll
    for (int j = 0; j < 16; ++j) {
        v1a[j] = -INFINITY; v2a[j] = -INFINITY;
        v1b[j] = -INFINITY; v2b[j] = -INFINITY;
    }

    // ncsq_s + lcount visible; stage(0) loads stay in flight (vmcnt untouched)
    asm volatile("s_waitcnt lgkmcnt(0)" ::: "memory");
    __builtin_amdgcn_sched_barrier(0);
    __builtin_amdgcn_s_barrier();

#pragma unroll 1
    for (int t = 0; t < NTILES; ++t) {
        const int b = t & 1;
        if (t + 1 < NTILES) {
            stage(t + 1, b ^ 1);                             // 4 more loads in flight
            asm volatile("s_waitcnt vmcnt(4)" ::: "memory"); // stage(t) done (mine)
        } else {
            asm volatile("s_waitcnt vmcnt(0)" ::: "memory"); // last tile: drain
        }
        __builtin_amdgcn_sched_barrier(0);
        __builtin_amdgcn_s_barrier();                        // stage(t) done (all waves)

        const float negcs = ncsq_s[t * 32 + col];            // LDS, conflict-free
        floatx16 acc0, acc1;                                 // acc init = -||e||^2
#pragma unroll
        for (int i = 0; i < 16; ++i) { acc0[i] = negcs; acc1[i] = negcs; }

        __builtin_amdgcn_s_setprio(1);
#pragma unroll
        for (int s = 0; s < 8; ++s) {
            short8_t bh = ebuf[b][0][s * 64 + lane];         // ds_read_b128, shared
            short8_t bl = ebuf[b][1][s * 64 + lane];         //   by both row-groups
            acc0 = __builtin_amdgcn_mfma_f32_32x32x16_bf16(ah0[s], bl, acc0, 0, 0, 0);
            acc1 = __builtin_amdgcn_mfma_f32_32x32x16_bf16(ah1[s], bl, acc1, 0, 0, 0);
            acc0 = __builtin_amdgcn_mfma_f32_32x32x16_bf16(al0[s], bh, acc0, 0, 0, 0);
            acc1 = __builtin_amdgcn_mfma_f32_32x32x16_bf16(al1[s], bh, acc1, 0, 0, 0);
            acc0 = __builtin_amdgcn_mfma_f32_32x32x16_bf16(ah0[s], bh, acc0, 0, 0, 0);
            acc1 = __builtin_amdgcn_mfma_f32_32x32x16_bf16(ah1[s], bh, acc1, 0, 0, 0);
        }
        __builtin_amdgcn_s_setprio(0);

        // epilogue: score already = 2 x.e - ||e||^2; tile id in mantissa LSBs
#pragma unroll
        for (int j = 0; j < 16; ++j) {
            unsigned u0 = (__float_as_uint(acc0[j]) & ~31u) | (unsigned)t;
            float cand0 = __uint_as_float(u0);
            float mn0 = fminf(v1a[j], cand0);
            v1a[j] = fmaxf(v1a[j], cand0);
            v2a[j] = fmaxf(v2a[j], mn0);
            unsigned u1 = (__float_as_uint(acc1[j]) & ~31u) | (unsigned)t;
            float cand1 = __uint_as_float(u1);
            float mn1 = fminf(v1b[j], cand1);
            v1b[j] = fmaxf(v1b[j], cand1);
            v2b[j] = fmaxf(v2b[j], mn1);
        }

        asm volatile("s_waitcnt lgkmcnt(0)" ::: "memory");   // my ds_reads of buf[t] done
        __builtin_amdgcn_sched_barrier(0);
        __builtin_amdgcn_s_barrier();                        // buf[t] free for stage(t+2)
    }

    // cross-lane top-2 merge over the 32 columns, per row-group
    auto merge_group = [&](float* v1, float* v2, int gbase) {
#pragma unroll
        for (int j = 0; j < 16; ++j) {
            float a1 = v1[j], a2 = v2[j];
            int   c1 = (int)((__float_as_uint(a1) & 31u) << 5) | col;   // tile*32 + col
#pragma unroll
            for (int m = 1; m < 32; m <<= 1) {
                float o1 = __shfl_xor(a1, m, 64);
                int   oc = __shfl_xor(c1, m, 64);
                float o2 = __shfl_xor(a2, m, 64);
                float lo = fminf(a1, o1);
                if (o1 > a1) { a1 = o1; c1 = oc; }
                a2 = fmaxf(fmaxf(a2, o2), lo);
            }
            if (col == j) {
                int row_local = gbase + (j & 3) + 8 * (j >> 2) + 4 * h;
                sidx[row_local] = c1;
                out_idx[rowblk + row_local] = (float)c1;
                if (a1 - a2 < TAU) {                      // ties always land here
                    unsigned p = atomicAdd(&lcount, 1u);  // <= 256 by construction
                    llist[p] = (unsigned char)row_local;
                }
            }
        }
    };
    merge_group(v1a, v2a, roww);
    merge_group(v1b, v2b, roww + 32);
    __syncthreads();

    // gather quantize = embed[best] (exact fp32 values, L2-hot)
    for (int i = tid; i < ROWS_BLK * 32; i += 256) {
        int r = i >> 5, q = i & 31;
        int code = sidx[r];
        float4 ev = *(const float4*)(embed + (size_t)code * D + q * 4);
        *(float4*)(out_q + (rowblk + r) * (long)D + q * 4) = ev;
    }
    __syncthreads();

    // fused exact fp32 recheck of this block's flagged rows (k-sequential
    // accumulation order preserved). Scratch aliases ebuf (loop is done).
    float* xs = (float*)&ebuf[0][0][0];           // 128 f32
    float* bv = xs + D;                           // 256 f32
    int*   bi = (int*)(bv + 256);                 // 256 i32
    const unsigned nf = lcount;
    const float4* eT = (const float4*)embT;       // [k][256 x float4-of-codes]
    for (unsigned f = 0; f < nf; ++f) {
        const int rl  = llist[f];
        const long row = rowblk + rl;
        if (tid < 32) *(float4*)&xs[tid * 4] = *(const float4*)(x + row * D + tid * 4);
        __syncthreads();
        float4 dot = {0.f, 0.f, 0.f, 0.f};
#pragma unroll 8
        for (int k = 0; k < D; ++k) {
            float xv = xs[k];
            float4 e = eT[(size_t)k * 256 + tid];
            dot.x = fmaf(xv, e.x, dot.x);
            dot.y = fmaf(xv, e.y, dot.y);
            dot.z = fmaf(xv, e.z, dot.z);
            dot.w = fmaf(xv, e.w, dot.w);
        }
        const int c0 = tid * 4;
        float scs[4] = {fmaf(2.f, dot.x, ncsq_s[c0]),
                        fmaf(2.f, dot.y, ncsq_s[c0 + 1]),
                        fmaf(2.f, dot.z, ncsq_s[c0 + 2]),
                        fmaf(2.f, dot.w, ncsq_s[c0 + 3])};
        float best = -INFINITY; int bidx = 0;
#pragma unroll
        for (int i = 0; i < 4; ++i)
            if (scs[i] > best) { best = scs[i]; bidx = c0 + i; }
        bv[tid] = best; bi[tid] = bidx;
        __syncthreads();
        for (int s = 128; s > 0; s >>= 1) {
            if (tid < s) {
                float ov = bv[tid + s]; int oi = bi[tid + s];
                if (ov > bv[tid] || (ov == bv[tid] && oi < bi[tid])) { bv[tid] = ov; bi[tid] = oi; }
            }
            __syncthreads();
        }
        const int win = bi[0];
        if (tid == 0) out_idx[row] = (float)win;
        if (tid < 32) {
            float4 ev = *(const float4*)(embed + (size_t)win * D + tid * 4);
            *(float4*)(out_q + row * D + tid * 4) = ev;
        }
        __syncthreads();
    }
}

extern "C" void kernel_launch(void* const* d_in, const int* in_sizes, int n_in,
                              void* d_out, int out_size, void* d_ws, size_t ws_size,
                              hipStream_t stream) {
    const float* x     = (const float*)d_in[0];
    const float* embed = (const float*)d_in[1];
    const int N = in_sizes[0] / D;   // 131072
    char* ws = (char*)d_ws;
    float*          ncsq = (float*)(ws + WS_NCSQ);
    unsigned short* ehi  = (unsigned short*)(ws + WS_EHI);
    unsigned short* elo  = (unsigned short*)(ws + WS_ELO);
    float*          embT = (float*)(ws + WS_EMBT);
    float* out_idx = (float*)d_out;
    float* out_q   = out_idx + N;

    hipLaunchKernelGGL(ecb_prep, dim3(64), dim3(256), 0, stream,
                       embed, ncsq, ehi, elo, embT);
    hipLaunchKernelGGL(ecb_main, dim3(N / ROWS_BLK), dim3(256), 0, stream,
                       x, ehi, elo, ncsq, embed, embT, out_idx, out_q);
}